// Round 7
// baseline (325.769 us; speedup 1.0000x reference)
//
#include <hip/hip_runtime.h>
#include <hip/hip_bf16.h>
#include <cmath>

#define BB 4
#define SS 2048
#define DD 1024
#define HH 16
#define DH 64
#define LDK 72   // padded LDS row stride for flash (bf16 elems)

typedef __attribute__((ext_vector_type(8))) short short8;
typedef __attribute__((ext_vector_type(4))) float floatx4;
typedef unsigned short u16;
typedef unsigned int u32;

// log2(e) folded with 1/sqrt(dh): scores come out in log2 domain
#define QSCALE 0.18033688011112042f   // 0.125 * 1.4426950408889634

__device__ __forceinline__ u16 f2bf(float f) {
    union { float f; u32 i; } u; u.f = f;
    u32 r = u.i + 0x7fff + ((u.i >> 16) & 1);   // RNE
    return (u16)(r >> 16);
}

// pack two floats -> (bf16(b)<<16)|bf16(a), round-half-up, 3 ops
__device__ __forceinline__ u32 pack_bf16(float a, float b) {
    union { float f; u32 i; } ua, ub; ua.f = a; ub.f = b;
    return __builtin_amdgcn_perm(ub.i + 0x8000u, ua.i + 0x8000u, 0x07060302u);
}

#if !__has_builtin(__builtin_amdgcn_exp2f)
#define __builtin_amdgcn_exp2f exp2f
#endif

// async global->LDS DMA, 16 B per lane; LDS dest = wave-uniform base + lane*16
__device__ __forceinline__ void async16(const u16* g, u16* l) {
    __builtin_amdgcn_global_load_lds(
        (const __attribute__((address_space(1))) unsigned int*)g,
        (__attribute__((address_space(3))) unsigned int*)l, 16, 0, 0);
}

// ---------------------------------------------------------------------------
// Cast X (8M elems) + 4 weight matrices (1M each) fp32 -> bf16, one launch.
// ---------------------------------------------------------------------------
__global__ __launch_bounds__(256)
void cast_all(const float* __restrict__ X,
              const float* __restrict__ w0, const float* __restrict__ w1,
              const float* __restrict__ w2, const float* __restrict__ w3,
              u16* __restrict__ Xb,
              u16* __restrict__ o0, u16* __restrict__ o1,
              u16* __restrict__ o2, u16* __restrict__ o3)
{
    int bid = blockIdx.x;
    const float* s; u16* d; int blk;
    if (bid < 4096) { s = X; d = Xb; blk = bid; }
    else {
        int t = bid - 4096;
        int wsel = t >> 9;  blk = t & 511;
        s = (wsel == 0) ? w0 : (wsel == 1) ? w1 : (wsel == 2) ? w2 : w3;
        d = (wsel == 0) ? o0 : (wsel == 1) ? o1 : (wsel == 2) ? o2 : o3;
    }
    int i = (blk * 256 + threadIdx.x) * 8;
    float4 f0 = *(const float4*)(s + i);
    float4 f1 = *(const float4*)(s + i + 4);
    u32 o[4];
    o[0] = pack_bf16(f0.x, f0.y); o[1] = pack_bf16(f0.z, f0.w);
    o[2] = pack_bf16(f1.x, f1.y); o[3] = pack_bf16(f1.z, f1.w);
    *(short8*)(d + i) = *(short8*)o;
}

// ---------------------------------------------------------------------------
// QKV projection: C = Xb @ W^T (MFMA bf16, global_load_lds + XOR-swizzled
// LDS layout: slot (row, s) holds global chunk s ^ (row&7) -> 2-way banks).
// Fused RoPE; Q pre-scaled by 0.125*log2(e).
// Q,K: [B,H,S,dh]. V: [B,H,dh,S] transposed.
// ---------------------------------------------------------------------------
__global__ __launch_bounds__(256)
void gemm_qkv(const u16* __restrict__ Xb,
              const u16* __restrict__ Wq, const u16* __restrict__ Wk, const u16* __restrict__ Wv,
              const int* __restrict__ pos,
              u16* __restrict__ Qb, u16* __restrict__ Kb, u16* __restrict__ Vtb)
{
    __shared__ __align__(16) u16 As[128 * 64];
    __shared__ __align__(16) u16 Bs[128 * 64];

    const int tid  = threadIdx.x;
    const int lane = tid & 63, w = tid >> 6;
    const int quad = lane >> 4, l16 = lane & 15;
    const int wr = w >> 1, wc = w & 1;
    const int m0 = blockIdx.x * 128, n0 = blockIdx.y * 128;
    const int which = blockIdx.z;
    const u16* __restrict__ W = (which == 0) ? Wq : (which == 1) ? Wk : Wv;

    // staging: lane (rs,cs) fetches global chunk cs^rs of row rs (XOR swizzle)
    const int rs_ = lane >> 3;                   // row 0..7 within 8-row group
    const int cs_ = lane & 7;                    // LDS chunk slot
    const int gcol = ((cs_ ^ rs_) << 3);         // swizzled global column
    const u16* gA = Xb + (size_t)(m0 + w * 32 + rs_) * DD + gcol;
    const u16* gB = W  + (size_t)(n0 + w * 32 + rs_) * DD + gcol;
    u16* lA = As + (w * 32) * 64;                // wave-uniform LDS base
    u16* lB = Bs + (w * 32) * 64;

    floatx4 acc[4][4];
    #pragma unroll
    for (int i = 0; i < 4; i++)
        #pragma unroll
        for (int j = 0; j < 4; j++) acc[i][j] = (floatx4)0.f;

    for (int kb = 0; kb < DD; kb += 64) {
        __syncthreads();   // previous compute done; LDS free
        #pragma unroll
        for (int j = 0; j < 4; j++) {
            async16(gA + (size_t)j * 8 * DD + kb, lA + j * 8 * 64);
            async16(gB + (size_t)j * 8 * DD + kb, lB + j * 8 * 64);
        }
        __syncthreads();   // vmcnt(0) drain: tiles visible
        #pragma unroll
        for (int ks = 0; ks < 2; ks++) {
            const int cx = ((ks * 4 + quad) ^ (l16 & 7)) << 3;  // de-swizzle
            short8 a[4], b[4];
            #pragma unroll
            for (int mi = 0; mi < 4; mi++)
                a[mi] = *(const short8*)&As[(wr * 64 + mi * 16 + l16) * 64 + cx];
            #pragma unroll
            for (int ni = 0; ni < 4; ni++)
                b[ni] = *(const short8*)&Bs[(wc * 64 + ni * 16 + l16) * 64 + cx];
            #pragma unroll
            for (int mi = 0; mi < 4; mi++)
                #pragma unroll
                for (int ni = 0; ni < 4; ni++)
                    acc[mi][ni] = __builtin_amdgcn_mfma_f32_16x16x32_bf16(a[mi], b[ni], acc[mi][ni], 0, 0, 0);
        }
    }

    const int colbase = n0 + wc * 64 + l16;
    const int rowbase = m0 + wr * 64 + quad * 4;
    u16* __restrict__ OutQK = (which == 0) ? Qb : Kb;

    #pragma unroll
    for (int ni = 0; ni < 4; ni++) {
        int col = colbase + ni * 16;
        int h = col >> 6, d = col & 63;
        float fr = __powf(10000.0f, -(float)(d & ~1) / 64.0f);
        bool evn = (d & 1) == 0;
        #pragma unroll
        for (int mi = 0; mi < 4; mi++) {
            int row0 = rowbase + mi * 16;
            if (which == 2) {
                int b = row0 >> 11, s0 = row0 & (SS - 1);
                ushort4 uv;
                uv.x = f2bf(acc[mi][ni][0]);
                uv.y = f2bf(acc[mi][ni][1]);
                uv.z = f2bf(acc[mi][ni][2]);
                uv.w = f2bf(acc[mi][ni][3]);
                *(ushort4*)&Vtb[((size_t)((b * HH + h) * DH + d)) * SS + s0] = uv;
            } else {
                #pragma unroll
                for (int r = 0; r < 4; r++) {
                    int row = row0 + r;
                    int b = row >> 11, s = row & (SS - 1);
                    float v = acc[mi][ni][r];
                    float other = __shfl_xor(v, 1);
                    float ang = (float)pos[s] * fr;
                    float sn, cs;
                    __sincosf(ang, &sn, &cs);
                    float res = evn ? (v * cs - other * sn) : (other * sn + v * cs);
                    if (which == 0) res *= QSCALE;   // 1/sqrt(dh) * log2(e)
                    OutQK[((size_t)((b * HH + h) * SS + s)) * DH + d] = f2bf(res);
                }
            }
        }
    }
}

// ---------------------------------------------------------------------------
// One 64x64 attention tile step for one q-tile (per-wave view).
// ---------------------------------------------------------------------------
__device__ __forceinline__ void attn_step(
    const u16* Ks, const u16* Vs, u16* Psw,
    const short8* qf, floatx4* oacc, float& m_run, float& l_run,
    const int l16, const int quad, const bool diag, const int qloc)
{
    floatx4 sacc[4];
    #pragma unroll
    for (int ni = 0; ni < 4; ni++) sacc[ni] = (floatx4)0.f;
    #pragma unroll
    for (int ks = 0; ks < 2; ks++) {
        #pragma unroll
        for (int ni = 0; ni < 4; ni++) {
            short8 kf = *(const short8*)&Ks[(ni * 16 + l16) * LDK + ks * 32 + quad * 8];
            sacc[ni] = __builtin_amdgcn_mfma_f32_16x16x32_bf16(kf, qf[ks], sacc[ni], 0, 0, 0);
        }
    }

    if (diag) {   // causal mask, diag tile only (block-uniform branch)
        #pragma unroll
        for (int ni = 0; ni < 4; ni++)
            #pragma unroll
            for (int r = 0; r < 4; r++)
                if (ni * 16 + quad * 4 + r > qloc) sacc[ni][r] = -__builtin_inff();
    }

    float mx01 = fmaxf(fmaxf(sacc[0][0], sacc[0][1]), fmaxf(sacc[0][2], sacc[0][3]));
    float mx23 = fmaxf(fmaxf(sacc[1][0], sacc[1][1]), fmaxf(sacc[1][2], sacc[1][3]));
    float mx45 = fmaxf(fmaxf(sacc[2][0], sacc[2][1]), fmaxf(sacc[2][2], sacc[2][3]));
    float mx67 = fmaxf(fmaxf(sacc[3][0], sacc[3][1]), fmaxf(sacc[3][2], sacc[3][3]));
    float mx = fmaxf(fmaxf(mx01, mx23), fmaxf(mx45, mx67));
    mx = fmaxf(mx, __shfl_xor(mx, 16));
    mx = fmaxf(mx, __shfl_xor(mx, 32));
    float mnew = fmaxf(m_run, mx);
    float al = __builtin_amdgcn_exp2f(m_run - mnew);

    float rs = 0.f;
    #pragma unroll
    for (int ni = 0; ni < 4; ni++) {
        float p0 = __builtin_amdgcn_exp2f(sacc[ni][0] - mnew);
        float p1 = __builtin_amdgcn_exp2f(sacc[ni][1] - mnew);
        float p2 = __builtin_amdgcn_exp2f(sacc[ni][2] - mnew);
        float p3 = __builtin_amdgcn_exp2f(sacc[ni][3] - mnew);
        rs += (p0 + p1) + (p2 + p3);
        u32 pk[2];
        pk[0] = pack_bf16(p0, p1);
        pk[1] = pack_bf16(p2, p3);
        *(uint2*)&Psw[l16 * LDK + ni * 16 + quad * 4] = *(uint2*)pk;
    }
    l_run = l_run * al + rs;   // per-lane partial; combined at end
    m_run = mnew;

    #pragma unroll
    for (int ni = 0; ni < 4; ni++) oacc[ni] *= al;
    #pragma unroll
    for (int ks = 0; ks < 2; ks++) {
        short8 pb = *(const short8*)&Psw[l16 * LDK + ks * 32 + quad * 8];
        #pragma unroll
        for (int ni = 0; ni < 4; ni++) {
            short8 vf = *(const short8*)&Vs[(ni * 16 + l16) * LDK + ks * 32 + quad * 8];
            oacc[ni] = __builtin_amdgcn_mfma_f32_16x16x32_bf16(vf, pb, oacc[ni], 0, 0, 0);
        }
    }
}

// ---------------------------------------------------------------------------
// Causal flash attention, MFMA bf16, transposed score tiles, exp2-domain
// softmax, reg-prefetch K/V pipeline, paired q-tiles {x, 31-x}.
// ---------------------------------------------------------------------------
__global__ __launch_bounds__(256)
void flash_mfma(const u16* __restrict__ Qb, const u16* __restrict__ Kb,
                const u16* __restrict__ Vtb, u16* __restrict__ AOb)
{
    __shared__ __align__(16) u16 Ks[64 * LDK];        // [key][d]
    __shared__ __align__(16) u16 Vs[64 * LDK];        // [d][key]
    __shared__ __align__(16) u16 Ps[4][2][16 * LDK];  // per-wave P strips (A,B)

    const int tid  = threadIdx.x;
    const int lane = tid & 63, w = tid >> 6;
    const int quad = lane >> 4, l16 = lane & 15;
    const int qtA = blockIdx.x;                 // 0..15  (light tile)
    const int qtB = (SS / 64 - 1) - blockIdx.x; // 31..16 (heavy tile)
    const int bh = blockIdx.y;
    const int b = bh >> 4, h = bh & 15;
    const size_t baseQK = (size_t)bh * SS * DH;
    const size_t baseVt = (size_t)bh * DH * SS;

    const int srow = tid >> 3;            // staging row 0..31 (+i*32)
    const int skc  = (tid & 7) << 3;

    const u16* QpA = Qb + baseQK + (size_t)(qtA * 64 + w * 16 + l16) * DH;
    const u16* QpB = Qb + baseQK + (size_t)(qtB * 64 + w * 16 + l16) * DH;
    short8 qfA[2], qfB[2];
    qfA[0] = *(const short8*)(QpA + quad * 8);
    qfA[1] = *(const short8*)(QpA + 32 + quad * 8);
    qfB[0] = *(const short8*)(QpB + quad * 8);
    qfB[1] = *(const short8*)(QpB + 32 + quad * 8);

    float mA = -__builtin_inff(), lA = 0.f;
    float mB = -__builtin_inff(), lB = 0.f;
    floatx4 oaccA[4], oaccB[4];
    #pragma unroll
    for (int ni = 0; ni < 4; ni++) { oaccA[ni] = (floatx4)0.f; oaccB[ni] = (floatx4)0.f; }

    const int qloc = w * 16 + l16;

    short8 kr[2], vr[2];
    #pragma unroll
    for (int i = 0; i < 2; i++) {
        int row = srow + i * 32;
        kr[i] = *(const short8*)(Kb + baseQK + (size_t)row * DH + skc);
        vr[i] = *(const short8*)(Vtb + baseVt + (size_t)row * SS + skc);
    }

    for (int kt = 0; kt <= qtB; kt++) {
        __syncthreads();
        #pragma unroll
        for (int i = 0; i < 2; i++) {
            int row = srow + i * 32;
            *(short8*)&Ks[row * LDK + skc] = kr[i];
            *(short8*)&Vs[row * LDK + skc] = vr[i];
        }
        __syncthreads();
        if (kt < qtB) {
            #pragma unroll
            for (int i = 0; i < 2; i++) {
                int row = srow + i * 32;
                kr[i] = *(const short8*)(Kb + baseQK + (size_t)((kt + 1) * 64 + row) * DH + skc);
                vr[i] = *(const short8*)(Vtb + baseVt + (size_t)row * SS + (kt + 1) * 64 + skc);
            }
        }

        if (kt <= qtA)
            attn_step(Ks, Vs, &Ps[w][0][0], qfA, oaccA, mA, lA,
                      l16, quad, kt == qtA, qloc);
        attn_step(Ks, Vs, &Ps[w][1][0], qfB, oaccB, mB, lB,
                  l16, quad, kt == qtB, qloc);
    }

    float lAt = lA;
    lAt += __shfl_xor(lAt, 16);
    lAt += __shfl_xor(lAt, 32);
    float lBt = lB;
    lBt += __shfl_xor(lBt, 16);
    lBt += __shfl_xor(lBt, 32);
    const float invlA = 1.f / lAt;
    const float invlB = 1.f / lBt;

    u16* dstA = AOb + (size_t)(b * SS + qtA * 64 + w * 16 + l16) * DD + h * DH;
    u16* dstB = AOb + (size_t)(b * SS + qtB * 64 + w * 16 + l16) * DD + h * DH;
    #pragma unroll
    for (int ni = 0; ni < 4; ni++) {
        u32 uo[2];
        uo[0] = pack_bf16(oaccA[ni][0] * invlA, oaccA[ni][1] * invlA);
        uo[1] = pack_bf16(oaccA[ni][2] * invlA, oaccA[ni][3] * invlA);
        *(uint2*)(dstA + ni * 16 + quad * 4) = *(uint2*)uo;
        uo[0] = pack_bf16(oaccB[ni][0] * invlB, oaccB[ni][1] * invlB);
        uo[1] = pack_bf16(oaccB[ni][2] * invlB, oaccB[ni][3] * invlB);
        *(uint2*)(dstB + ni * 16 + quad * 4) = *(uint2*)uo;
    }
}

// ---------------------------------------------------------------------------
// Output projection: out = AO @ wo^T (bf16 MFMA, async DMA + XOR swizzle,
// fp32 out)
// ---------------------------------------------------------------------------
__global__ __launch_bounds__(256)
void gemm_out(const u16* __restrict__ A, const u16* __restrict__ W, float* __restrict__ C)
{
    __shared__ __align__(16) u16 As[128 * 64];
    __shared__ __align__(16) u16 Bs[128 * 64];

    const int tid  = threadIdx.x;
    const int lane = tid & 63, w = tid >> 6;
    const int quad = lane >> 4, l16 = lane & 15;
    const int wr = w >> 1, wc = w & 1;
    const int m0 = blockIdx.x * 128, n0 = blockIdx.y * 128;

    const int rs_ = lane >> 3;
    const int cs_ = lane & 7;
    const int gcol = ((cs_ ^ rs_) << 3);
    const u16* gA = A + (size_t)(m0 + w * 32 + rs_) * DD + gcol;
    const u16* gB = W + (size_t)(n0 + w * 32 + rs_) * DD + gcol;
    u16* lA = As + (w * 32) * 64;
    u16* lB = Bs + (w * 32) * 64;

    floatx4 acc[4][4];
    #pragma unroll
    for (int i = 0; i < 4; i++)
        #pragma unroll
        for (int j = 0; j < 4; j++) acc[i][j] = (floatx4)0.f;

    for (int kb = 0; kb < DD; kb += 64) {
        __syncthreads();
        #pragma unroll
        for (int j = 0; j < 4; j++) {
            async16(gA + (size_t)j * 8 * DD + kb, lA + j * 8 * 64);
            async16(gB + (size_t)j * 8 * DD + kb, lB + j * 8 * 64);
        }
        __syncthreads();
        #pragma unroll
        for (int ks = 0; ks < 2; ks++) {
            const int cx = ((ks * 4 + quad) ^ (l16 & 7)) << 3;
            short8 a[4], b[4];
            #pragma unroll
            for (int mi = 0; mi < 4; mi++)
                a[mi] = *(const short8*)&As[(wr * 64 + mi * 16 + l16) * 64 + cx];
            #pragma unroll
            for (int ni = 0; ni < 4; ni++)
                b[ni] = *(const short8*)&Bs[(wc * 64 + ni * 16 + l16) * 64 + cx];
            #pragma unroll
            for (int mi = 0; mi < 4; mi++)
                #pragma unroll
                for (int ni = 0; ni < 4; ni++)
                    acc[mi][ni] = __builtin_amdgcn_mfma_f32_16x16x32_bf16(a[mi], b[ni], acc[mi][ni], 0, 0, 0);
        }
    }

    const int colbase = n0 + wc * 64 + l16;
    const int rowbase = m0 + wr * 64 + quad * 4;
    #pragma unroll
    for (int ni = 0; ni < 4; ni++) {
        int col = colbase + ni * 16;
        #pragma unroll
        for (int mi = 0; mi < 4; mi++) {
            int row0 = rowbase + mi * 16;
            #pragma unroll
            for (int r = 0; r < 4; r++)
                C[(size_t)(row0 + r) * DD + col] = acc[mi][ni][r];
        }
    }
}

extern "C" void kernel_launch(void* const* d_in, const int* in_sizes, int n_in,
                              void* d_out, int out_size, void* d_ws, size_t ws_size,
                              hipStream_t stream) {
    const float* X  = (const float*)d_in[0];
    const int* pos  = (const int*)d_in[1];
    const float* wq = (const float*)d_in[2];
    const float* wk = (const float*)d_in[3];
    const float* wv = (const float*)d_in[4];
    const float* wo = (const float*)d_in[5];
    float* out = (float*)d_out;

    const size_t wsz = (size_t)DD * DD;            // 1M elems
    const size_t qsz = (size_t)BB * HH * SS * DH;  // 8M elems
    u16* Wqb = (u16*)d_ws;
    u16* Wkb = Wqb + wsz;
    u16* Wvb = Wkb + wsz;
    u16* Wob = Wvb + wsz;
    u16* Qb  = Wob + wsz;
    u16* Kb  = Qb + qsz;
    u16* Vtb = Kb + qsz;
    u16* Xb  = Vtb + qsz;   // aliased: Xb used by gemm_qkv, then reused as AOb
    u16* AOb = Xb;          // flash writes after gemm_qkv finishes reading Xb

    dim3 blk(256);
    cast_all<<<dim3(4096 + 4 * 512), blk, 0, stream>>>(X, wq, wk, wv, wo,
                                                       Xb, Wqb, Wkb, Wvb, Wob);
    gemm_qkv<<<dim3((BB * SS) / 128, DD / 128, 3), blk, 0, stream>>>(Xb, Wqb, Wkb, Wvb, pos, Qb, Kb, Vtb);
    flash_mfma<<<dim3(SS / 128, BB * HH), blk, 0, stream>>>(Qb, Kb, Vtb, AOb);
    gemm_out<<<dim3((BB * SS) / 128, DD / 128), blk, 0, stream>>>(AOb, Wob, out);
}

// Round 8
// 273.640 us; speedup vs baseline: 1.1905x; 1.1905x over previous
//
#include <hip/hip_runtime.h>
#include <hip/hip_bf16.h>
#include <cmath>

#define BB 4
#define SS 2048
#define DD 1024
#define HH 16
#define DH 64
#define LDK 72   // padded LDS row stride for flash (bf16 elems)

typedef __attribute__((ext_vector_type(8))) short short8;
typedef __attribute__((ext_vector_type(4))) float floatx4;
typedef unsigned short u16;
typedef unsigned int u32;

// log2(e) folded with 1/sqrt(dh): scores come out in log2 domain
#define QSCALE 0.18033688011112042f   // 0.125 * 1.4426950408889634

__device__ __forceinline__ u16 f2bf(float f) {
    union { float f; u32 i; } u; u.f = f;
    u32 r = u.i + 0x7fff + ((u.i >> 16) & 1);   // RNE
    return (u16)(r >> 16);
}

// pack two floats -> (bf16(b)<<16)|bf16(a), round-half-up, 3 ops
__device__ __forceinline__ u32 pack_bf16(float a, float b) {
    union { float f; u32 i; } ua, ub; ua.f = a; ub.f = b;
    return __builtin_amdgcn_perm(ub.i + 0x8000u, ua.i + 0x8000u, 0x07060302u);
}

#if !__has_builtin(__builtin_amdgcn_exp2f)
#define __builtin_amdgcn_exp2f exp2f
#endif

// async global->LDS DMA, 16 B per lane; LDS dest = wave-uniform base + lane*16
__device__ __forceinline__ void async16(const u16* g, u16* l) {
    __builtin_amdgcn_global_load_lds(
        (const __attribute__((address_space(1))) unsigned int*)g,
        (__attribute__((address_space(3))) unsigned int*)l, 16, 0, 0);
}

// ---------------------------------------------------------------------------
// Cast X (8M elems) + 4 weight matrices (1M each) fp32 -> bf16, one launch.
// ---------------------------------------------------------------------------
__global__ __launch_bounds__(256)
void cast_all(const float* __restrict__ X,
              const float* __restrict__ w0, const float* __restrict__ w1,
              const float* __restrict__ w2, const float* __restrict__ w3,
              u16* __restrict__ Xb,
              u16* __restrict__ o0, u16* __restrict__ o1,
              u16* __restrict__ o2, u16* __restrict__ o3)
{
    int bid = blockIdx.x;
    const float* s; u16* d; int blk;
    if (bid < 4096) { s = X; d = Xb; blk = bid; }
    else {
        int t = bid - 4096;
        int wsel = t >> 9;  blk = t & 511;
        s = (wsel == 0) ? w0 : (wsel == 1) ? w1 : (wsel == 2) ? w2 : w3;
        d = (wsel == 0) ? o0 : (wsel == 1) ? o1 : (wsel == 2) ? o2 : o3;
    }
    int i = (blk * 256 + threadIdx.x) * 8;
    float4 f0 = *(const float4*)(s + i);
    float4 f1 = *(const float4*)(s + i + 4);
    u32 o[4];
    o[0] = pack_bf16(f0.x, f0.y); o[1] = pack_bf16(f0.z, f0.w);
    o[2] = pack_bf16(f1.x, f1.y); o[3] = pack_bf16(f1.z, f1.w);
    *(short8*)(d + i) = *(short8*)o;
}

// ---------------------------------------------------------------------------
// QKV projection: C = Xb @ W^T (MFMA bf16, global_load_lds + XOR-swizzled
// LDS layout: slot (row, s) holds global chunk s ^ (row&7) -> conflict-free).
// __launch_bounds__(256,4): cap VGPR at 128 so 4 blocks/CU resident.
// Fused RoPE; Q pre-scaled by 0.125*log2(e).
// Q,K: [B,H,S,dh]. V: [B,H,dh,S] transposed.
// ---------------------------------------------------------------------------
__global__ __launch_bounds__(256, 4)
void gemm_qkv(const u16* __restrict__ Xb,
              const u16* __restrict__ Wq, const u16* __restrict__ Wk, const u16* __restrict__ Wv,
              const int* __restrict__ pos,
              u16* __restrict__ Qb, u16* __restrict__ Kb, u16* __restrict__ Vtb)
{
    __shared__ __align__(16) u16 As[128 * 64];
    __shared__ __align__(16) u16 Bs[128 * 64];

    const int tid  = threadIdx.x;
    const int lane = tid & 63, w = tid >> 6;
    const int quad = lane >> 4, l16 = lane & 15;
    const int wr = w >> 1, wc = w & 1;
    const int m0 = blockIdx.x * 128, n0 = blockIdx.y * 128;
    const int which = blockIdx.z;
    const u16* __restrict__ W = (which == 0) ? Wq : (which == 1) ? Wk : Wv;

    // staging: lane (rs,cs) fetches global chunk cs^rs of row rs (XOR swizzle)
    const int rs_ = lane >> 3;                   // row 0..7 within 8-row group
    const int cs_ = lane & 7;                    // LDS chunk slot
    const int gcol = ((cs_ ^ rs_) << 3);         // swizzled global column
    const u16* gA = Xb + (size_t)(m0 + w * 32 + rs_) * DD + gcol;
    const u16* gB = W  + (size_t)(n0 + w * 32 + rs_) * DD + gcol;
    u16* lA = As + (w * 32) * 64;                // wave-uniform LDS base
    u16* lB = Bs + (w * 32) * 64;

    floatx4 acc[4][4];
    #pragma unroll
    for (int i = 0; i < 4; i++)
        #pragma unroll
        for (int j = 0; j < 4; j++) acc[i][j] = (floatx4)0.f;

    for (int kb = 0; kb < DD; kb += 64) {
        __syncthreads();   // previous compute done; LDS free
        #pragma unroll
        for (int j = 0; j < 4; j++) {
            async16(gA + (size_t)j * 8 * DD + kb, lA + j * 8 * 64);
            async16(gB + (size_t)j * 8 * DD + kb, lB + j * 8 * 64);
        }
        __syncthreads();   // vmcnt(0) drain: tiles visible
        #pragma unroll
        for (int ks = 0; ks < 2; ks++) {
            const int cx = ((ks * 4 + quad) ^ (l16 & 7)) << 3;  // de-swizzle
            short8 a[4], b[4];
            #pragma unroll
            for (int mi = 0; mi < 4; mi++)
                a[mi] = *(const short8*)&As[(wr * 64 + mi * 16 + l16) * 64 + cx];
            #pragma unroll
            for (int ni = 0; ni < 4; ni++)
                b[ni] = *(const short8*)&Bs[(wc * 64 + ni * 16 + l16) * 64 + cx];
            #pragma unroll
            for (int mi = 0; mi < 4; mi++)
                #pragma unroll
                for (int ni = 0; ni < 4; ni++)
                    acc[mi][ni] = __builtin_amdgcn_mfma_f32_16x16x32_bf16(a[mi], b[ni], acc[mi][ni], 0, 0, 0);
        }
    }

    const int colbase = n0 + wc * 64 + l16;
    const int rowbase = m0 + wr * 64 + quad * 4;
    u16* __restrict__ OutQK = (which == 0) ? Qb : Kb;

    #pragma unroll
    for (int ni = 0; ni < 4; ni++) {
        int col = colbase + ni * 16;
        int h = col >> 6, d = col & 63;
        float fr = __powf(10000.0f, -(float)(d & ~1) / 64.0f);
        bool evn = (d & 1) == 0;
        #pragma unroll
        for (int mi = 0; mi < 4; mi++) {
            int row0 = rowbase + mi * 16;
            if (which == 2) {
                int b = row0 >> 11, s0 = row0 & (SS - 1);
                ushort4 uv;
                uv.x = f2bf(acc[mi][ni][0]);
                uv.y = f2bf(acc[mi][ni][1]);
                uv.z = f2bf(acc[mi][ni][2]);
                uv.w = f2bf(acc[mi][ni][3]);
                *(ushort4*)&Vtb[((size_t)((b * HH + h) * DH + d)) * SS + s0] = uv;
            } else {
                #pragma unroll
                for (int r = 0; r < 4; r++) {
                    int row = row0 + r;
                    int b = row >> 11, s = row & (SS - 1);
                    float v = acc[mi][ni][r];
                    float other = __shfl_xor(v, 1);
                    float ang = (float)pos[s] * fr;
                    float sn, cs;
                    __sincosf(ang, &sn, &cs);
                    float res = evn ? (v * cs - other * sn) : (other * sn + v * cs);
                    if (which == 0) res *= QSCALE;   // 1/sqrt(dh) * log2(e)
                    OutQK[((size_t)((b * HH + h) * SS + s)) * DH + d] = f2bf(res);
                }
            }
        }
    }
}

// ---------------------------------------------------------------------------
// One 64x64 attention tile step for one q-tile (per-wave view).
// ---------------------------------------------------------------------------
__device__ __forceinline__ void attn_step(
    const u16* Ks, const u16* Vs, u16* Psw,
    const short8* qf, floatx4* oacc, float& m_run, float& l_run,
    const int l16, const int quad, const bool diag, const int qloc)
{
    floatx4 sacc[4];
    #pragma unroll
    for (int ni = 0; ni < 4; ni++) sacc[ni] = (floatx4)0.f;
    #pragma unroll
    for (int ks = 0; ks < 2; ks++) {
        #pragma unroll
        for (int ni = 0; ni < 4; ni++) {
            short8 kf = *(const short8*)&Ks[(ni * 16 + l16) * LDK + ks * 32 + quad * 8];
            sacc[ni] = __builtin_amdgcn_mfma_f32_16x16x32_bf16(kf, qf[ks], sacc[ni], 0, 0, 0);
        }
    }

    if (diag) {   // causal mask, diag tile only (block-uniform branch)
        #pragma unroll
        for (int ni = 0; ni < 4; ni++)
            #pragma unroll
            for (int r = 0; r < 4; r++)
                if (ni * 16 + quad * 4 + r > qloc) sacc[ni][r] = -__builtin_inff();
    }

    float mx01 = fmaxf(fmaxf(sacc[0][0], sacc[0][1]), fmaxf(sacc[0][2], sacc[0][3]));
    float mx23 = fmaxf(fmaxf(sacc[1][0], sacc[1][1]), fmaxf(sacc[1][2], sacc[1][3]));
    float mx45 = fmaxf(fmaxf(sacc[2][0], sacc[2][1]), fmaxf(sacc[2][2], sacc[2][3]));
    float mx67 = fmaxf(fmaxf(sacc[3][0], sacc[3][1]), fmaxf(sacc[3][2], sacc[3][3]));
    float mx = fmaxf(fmaxf(mx01, mx23), fmaxf(mx45, mx67));
    mx = fmaxf(mx, __shfl_xor(mx, 16));
    mx = fmaxf(mx, __shfl_xor(mx, 32));
    float mnew = fmaxf(m_run, mx);
    float al = __builtin_amdgcn_exp2f(m_run - mnew);

    float rs = 0.f;
    #pragma unroll
    for (int ni = 0; ni < 4; ni++) {
        float p0 = __builtin_amdgcn_exp2f(sacc[ni][0] - mnew);
        float p1 = __builtin_amdgcn_exp2f(sacc[ni][1] - mnew);
        float p2 = __builtin_amdgcn_exp2f(sacc[ni][2] - mnew);
        float p3 = __builtin_amdgcn_exp2f(sacc[ni][3] - mnew);
        rs += (p0 + p1) + (p2 + p3);
        u32 pk[2];
        pk[0] = pack_bf16(p0, p1);
        pk[1] = pack_bf16(p2, p3);
        *(uint2*)&Psw[l16 * LDK + ni * 16 + quad * 4] = *(uint2*)pk;
    }
    l_run = l_run * al + rs;   // per-lane partial; combined at end
    m_run = mnew;

    #pragma unroll
    for (int ni = 0; ni < 4; ni++) oacc[ni] *= al;
    #pragma unroll
    for (int ks = 0; ks < 2; ks++) {
        short8 pb = *(const short8*)&Psw[l16 * LDK + ks * 32 + quad * 8];
        #pragma unroll
        for (int ni = 0; ni < 4; ni++) {
            short8 vf = *(const short8*)&Vs[(ni * 16 + l16) * LDK + ks * 32 + quad * 8];
            oacc[ni] = __builtin_amdgcn_mfma_f32_16x16x32_bf16(vf, pb, oacc[ni], 0, 0, 0);
        }
    }
}

// ---------------------------------------------------------------------------
// Causal flash attention, MFMA bf16, transposed score tiles, exp2-domain
// softmax, reg-prefetch K/V pipeline, paired q-tiles {x, 31-x}.
// ---------------------------------------------------------------------------
__global__ __launch_bounds__(256)
void flash_mfma(const u16* __restrict__ Qb, const u16* __restrict__ Kb,
                const u16* __restrict__ Vtb, u16* __restrict__ AOb)
{
    __shared__ __align__(16) u16 Ks[64 * LDK];        // [key][d]
    __shared__ __align__(16) u16 Vs[64 * LDK];        // [d][key]
    __shared__ __align__(16) u16 Ps[4][2][16 * LDK];  // per-wave P strips (A,B)

    const int tid  = threadIdx.x;
    const int lane = tid & 63, w = tid >> 6;
    const int quad = lane >> 4, l16 = lane & 15;
    const int qtA = blockIdx.x;                 // 0..15  (light tile)
    const int qtB = (SS / 64 - 1) - blockIdx.x; // 31..16 (heavy tile)
    const int bh = blockIdx.y;
    const int b = bh >> 4, h = bh & 15;
    const size_t baseQK = (size_t)bh * SS * DH;
    const size_t baseVt = (size_t)bh * DH * SS;

    const int srow = tid >> 3;            // staging row 0..31 (+i*32)
    const int skc  = (tid & 7) << 3;

    const u16* QpA = Qb + baseQK + (size_t)(qtA * 64 + w * 16 + l16) * DH;
    const u16* QpB = Qb + baseQK + (size_t)(qtB * 64 + w * 16 + l16) * DH;
    short8 qfA[2], qfB[2];
    qfA[0] = *(const short8*)(QpA + quad * 8);
    qfA[1] = *(const short8*)(QpA + 32 + quad * 8);
    qfB[0] = *(const short8*)(QpB + quad * 8);
    qfB[1] = *(const short8*)(QpB + 32 + quad * 8);

    float mA = -__builtin_inff(), lA = 0.f;
    float mB = -__builtin_inff(), lB = 0.f;
    floatx4 oaccA[4], oaccB[4];
    #pragma unroll
    for (int ni = 0; ni < 4; ni++) { oaccA[ni] = (floatx4)0.f; oaccB[ni] = (floatx4)0.f; }

    const int qloc = w * 16 + l16;

    short8 kr[2], vr[2];
    #pragma unroll
    for (int i = 0; i < 2; i++) {
        int row = srow + i * 32;
        kr[i] = *(const short8*)(Kb + baseQK + (size_t)row * DH + skc);
        vr[i] = *(const short8*)(Vtb + baseVt + (size_t)row * SS + skc);
    }

    for (int kt = 0; kt <= qtB; kt++) {
        __syncthreads();
        #pragma unroll
        for (int i = 0; i < 2; i++) {
            int row = srow + i * 32;
            *(short8*)&Ks[row * LDK + skc] = kr[i];
            *(short8*)&Vs[row * LDK + skc] = vr[i];
        }
        __syncthreads();
        if (kt < qtB) {
            #pragma unroll
            for (int i = 0; i < 2; i++) {
                int row = srow + i * 32;
                kr[i] = *(const short8*)(Kb + baseQK + (size_t)((kt + 1) * 64 + row) * DH + skc);
                vr[i] = *(const short8*)(Vtb + baseVt + (size_t)row * SS + (kt + 1) * 64 + skc);
            }
        }

        if (kt <= qtA)
            attn_step(Ks, Vs, &Ps[w][0][0], qfA, oaccA, mA, lA,
                      l16, quad, kt == qtA, qloc);
        attn_step(Ks, Vs, &Ps[w][1][0], qfB, oaccB, mB, lB,
                  l16, quad, kt == qtB, qloc);
    }

    float lAt = lA;
    lAt += __shfl_xor(lAt, 16);
    lAt += __shfl_xor(lAt, 32);
    float lBt = lB;
    lBt += __shfl_xor(lBt, 16);
    lBt += __shfl_xor(lBt, 32);
    const float invlA = 1.f / lAt;
    const float invlB = 1.f / lBt;

    u16* dstA = AOb + (size_t)(b * SS + qtA * 64 + w * 16 + l16) * DD + h * DH;
    u16* dstB = AOb + (size_t)(b * SS + qtB * 64 + w * 16 + l16) * DD + h * DH;
    #pragma unroll
    for (int ni = 0; ni < 4; ni++) {
        u32 uo[2];
        uo[0] = pack_bf16(oaccA[ni][0] * invlA, oaccA[ni][1] * invlA);
        uo[1] = pack_bf16(oaccA[ni][2] * invlA, oaccA[ni][3] * invlA);
        *(uint2*)(dstA + ni * 16 + quad * 4) = *(uint2*)uo;
        uo[0] = pack_bf16(oaccB[ni][0] * invlB, oaccB[ni][1] * invlB);
        uo[1] = pack_bf16(oaccB[ni][2] * invlB, oaccB[ni][3] * invlB);
        *(uint2*)(dstB + ni * 16 + quad * 4) = *(uint2*)uo;
    }
}

// ---------------------------------------------------------------------------
// Output projection: out = AO @ wo^T (bf16 MFMA, async DMA + XOR swizzle,
// __launch_bounds__(256,4) for 4 blocks/CU, fp32 out)
// ---------------------------------------------------------------------------
__global__ __launch_bounds__(256, 4)
void gemm_out(const u16* __restrict__ A, const u16* __restrict__ W, float* __restrict__ C)
{
    __shared__ __align__(16) u16 As[128 * 64];
    __shared__ __align__(16) u16 Bs[128 * 64];

    const int tid  = threadIdx.x;
    const int lane = tid & 63, w = tid >> 6;
    const int quad = lane >> 4, l16 = lane & 15;
    const int wr = w >> 1, wc = w & 1;
    const int m0 = blockIdx.x * 128, n0 = blockIdx.y * 128;

    const int rs_ = lane >> 3;
    const int cs_ = lane & 7;
    const int gcol = ((cs_ ^ rs_) << 3);
    const u16* gA = A + (size_t)(m0 + w * 32 + rs_) * DD + gcol;
    const u16* gB = W + (size_t)(n0 + w * 32 + rs_) * DD + gcol;
    u16* lA = As + (w * 32) * 64;
    u16* lB = Bs + (w * 32) * 64;

    floatx4 acc[4][4];
    #pragma unroll
    for (int i = 0; i < 4; i++)
        #pragma unroll
        for (int j = 0; j < 4; j++) acc[i][j] = (floatx4)0.f;

    for (int kb = 0; kb < DD; kb += 64) {
        __syncthreads();
        #pragma unroll
        for (int j = 0; j < 4; j++) {
            async16(gA + (size_t)j * 8 * DD + kb, lA + j * 8 * 64);
            async16(gB + (size_t)j * 8 * DD + kb, lB + j * 8 * 64);
        }
        __syncthreads();
        #pragma unroll
        for (int ks = 0; ks < 2; ks++) {
            const int cx = ((ks * 4 + quad) ^ (l16 & 7)) << 3;
            short8 a[4], b[4];
            #pragma unroll
            for (int mi = 0; mi < 4; mi++)
                a[mi] = *(const short8*)&As[(wr * 64 + mi * 16 + l16) * 64 + cx];
            #pragma unroll
            for (int ni = 0; ni < 4; ni++)
                b[ni] = *(const short8*)&Bs[(wc * 64 + ni * 16 + l16) * 64 + cx];
            #pragma unroll
            for (int mi = 0; mi < 4; mi++)
                #pragma unroll
                for (int ni = 0; ni < 4; ni++)
                    acc[mi][ni] = __builtin_amdgcn_mfma_f32_16x16x32_bf16(a[mi], b[ni], acc[mi][ni], 0, 0, 0);
        }
    }

    const int colbase = n0 + wc * 64 + l16;
    const int rowbase = m0 + wr * 64 + quad * 4;
    #pragma unroll
    for (int ni = 0; ni < 4; ni++) {
        int col = colbase + ni * 16;
        #pragma unroll
        for (int mi = 0; mi < 4; mi++) {
            int row0 = rowbase + mi * 16;
            #pragma unroll
            for (int r = 0; r < 4; r++)
                C[(size_t)(row0 + r) * DD + col] = acc[mi][ni][r];
        }
    }
}

extern "C" void kernel_launch(void* const* d_in, const int* in_sizes, int n_in,
                              void* d_out, int out_size, void* d_ws, size_t ws_size,
                              hipStream_t stream) {
    const float* X  = (const float*)d_in[0];
    const int* pos  = (const int*)d_in[1];
    const float* wq = (const float*)d_in[2];
    const float* wk = (const float*)d_in[3];
    const float* wv = (const float*)d_in[4];
    const float* wo = (const float*)d_in[5];
    float* out = (float*)d_out;

    const size_t wsz = (size_t)DD * DD;            // 1M elems
    const size_t qsz = (size_t)BB * HH * SS * DH;  // 8M elems
    u16* Wqb = (u16*)d_ws;
    u16* Wkb = Wqb + wsz;
    u16* Wvb = Wkb + wsz;
    u16* Wob = Wvb + wsz;
    u16* Qb  = Wob + wsz;
    u16* Kb  = Qb + qsz;
    u16* Vtb = Kb + qsz;
    u16* Xb  = Vtb + qsz;   // aliased: Xb used by gemm_qkv, then reused as AOb
    u16* AOb = Xb;          // flash writes after gemm_qkv finishes reading Xb

    dim3 blk(256);
    cast_all<<<dim3(4096 + 4 * 512), blk, 0, stream>>>(X, wq, wk, wv, wo,
                                                       Xb, Wqb, Wkb, Wvb, Wob);
    gemm_qkv<<<dim3((BB * SS) / 128, DD / 128, 3), blk, 0, stream>>>(Xb, Wqb, Wkb, Wvb, pos, Qb, Kb, Vtb);
    flash_mfma<<<dim3(SS / 128, BB * HH), blk, 0, stream>>>(Qb, Kb, Vtb, AOb);
    gemm_out<<<dim3((BB * SS) / 128, DD / 128), blk, 0, stream>>>(AOb, Wob, out);
}